// Round 2
// baseline (343.844 us; speedup 1.0000x reference)
//
#include <hip/hip_runtime.h>
#include <hip/hip_bf16.h>

typedef __attribute__((ext_vector_type(8))) short bf16x8;
typedef __attribute__((ext_vector_type(4))) float f32x4;
typedef __attribute__((ext_vector_type(4))) unsigned int u32x4;

#define NC 32
#define HH 512
#define WWD 512
#define HW (HH * WWD)

#define TH 8
#define TW 64
#define HALO_W 66
#define ROWS 10                  // circular row slots in LDS
#define NITER 16                 // 16 * TH = 128 rows per block
#define XBYTES (ROWS * HALO_W * 64)   // 42240 B: [slot*66+ww][ic] bf16, swizzled
#define WOFF XBYTES                   // weights at +42240, 18432 B
#define NU8  (8 * HALO_W * 4)    // 2112 load units, steady state
#define NU10 (ROWS * HALO_W * 4) // 2640 load units, prologue

__device__ __forceinline__ unsigned short f2bf(float f) {
    unsigned u = __builtin_bit_cast(unsigned, f);
    u += 0x7FFFu + ((u >> 16) & 1u);   // round-to-nearest-even
    return (unsigned short)(u >> 16);
}

__device__ __forceinline__ int xbyte(int p, int g) {
    return (p * 64 + g * 16) ^ ((p & 7) << 4);   // conflict-free swizzle
}

__global__ __launch_bounds__(512, 4)
void conv3x3_mfma(const float* __restrict__ x,
                  const float* __restrict__ wk,
                  float* __restrict__ out) {
    __shared__ __align__(16) char smem[XBYTES + 9 * 32 * 32 * 2];  // 60672 B

    const int tid   = threadIdx.x;
    const int lane  = tid & 63;
    const int wv    = tid >> 6;
    const int col16 = lane & 15;
    const int g4    = lane >> 4;

    const int w0    = blockIdx.x * TW;
    const int hbase = blockIdx.y * (TH * NITER);
    const int b     = blockIdx.z;

    const float* xb = x + (size_t)b * NC * HW;
    float* ob = out + (size_t)b * NC * HW;

    float sv[6][8];

    // ---- prologue: issue 10-row x load (rows hbase-1 .. hbase+8 -> slots 0..9) ----
    #pragma unroll
    for (int k = 0; k < 6; ++k) {
        int u = tid + k * 512;
        if (u < NU10) {
            int g  = u / (ROWS * HALO_W);
            int p  = u - g * (ROWS * HALO_W);
            int hh = p / HALO_W;
            int ww = p - hh * HALO_W;
            int row = hbase + hh - 1;
            int cl  = w0 + ww - 1;
            bool ok = ((unsigned)row < (unsigned)HH) && ((unsigned)cl < (unsigned)WWD);
            const float* src = xb + (g * 8) * HW + row * WWD + cl;
            #pragma unroll
            for (int j = 0; j < 8; ++j) {
                float t = 0.f;
                if (ok) t = src[j * HW];
                sv[k][j] = t;
            }
        }
    }

    // ---- weights -> LDS bf16, layout [tap][oc][ic] (B-frag = 16B contiguous) ----
    {
        unsigned short* wl = (unsigned short*)(smem + WOFF);
        for (int i = tid; i < 9216; i += 512) {
            int oc = i / 288; int rem = i - oc * 288;
            int ic = rem / 9; int tap = rem - ic * 9;
            wl[(tap * 32 + oc) * 32 + ic] = f2bf(wk[i]);
        }
    }

    // ---- write prologue rows to LDS (slot = hh) ----
    #pragma unroll
    for (int k = 0; k < 6; ++k) {
        int u = tid + k * 512;
        if (u < NU10) {
            int g = u / (ROWS * HALO_W);
            int p = u - g * (ROWS * HALO_W);   // slot*66+ww directly
            unsigned q0 = (unsigned)f2bf(sv[k][0]) | ((unsigned)f2bf(sv[k][1]) << 16);
            unsigned q1 = (unsigned)f2bf(sv[k][2]) | ((unsigned)f2bf(sv[k][3]) << 16);
            unsigned q2 = (unsigned)f2bf(sv[k][4]) | ((unsigned)f2bf(sv[k][5]) << 16);
            unsigned q3 = (unsigned)f2bf(sv[k][6]) | ((unsigned)f2bf(sv[k][7]) << 16);
            u32x4 q = { q0, q1, q2, q3 };
            *(u32x4*)(smem + xbyte(p, g)) = q;
        }
    }

    // ---- prefetch rows for iter 1: r_rel 9..16 ----
    #pragma unroll
    for (int k = 0; k < 5; ++k) {
        int u = tid + k * 512;
        if (u < NU8) {
            int g  = u / (8 * HALO_W);
            int p  = u - g * (8 * HALO_W);
            int hh = p / HALO_W;
            int ww = p - hh * HALO_W;
            int row = hbase + 9 + hh;
            int cl  = w0 + ww - 1;
            bool ok = ((unsigned)row < (unsigned)HH) && ((unsigned)cl < (unsigned)WWD);
            const float* src = xb + (g * 8) * HW + row * WWD + cl;
            #pragma unroll
            for (int j = 0; j < 8; ++j) {
                float t = 0.f;
                if (ok) t = src[j * HW];
                sv[k][j] = t;
            }
        }
    }

    __syncthreads();   // weights + tile 0 visible

    int srbase = wv;   // (8*it + wv) % 10
    int wb = 0;        // (8*it) % 10 : slot base for the write at tail of iter it

    for (int it = 0; it < NITER; ++it) {
        // ---- compute: wave wv owns output row hbase+8*it+wv ----
        f32x4 acc[4][2];
        #pragma unroll
        for (int m = 0; m < 4; ++m) {
            f32x4 z = {0.f, 0.f, 0.f, 0.f};
            acc[m][0] = z; acc[m][1] = z;
        }

        int rs[3];
        #pragma unroll
        for (int dh = 0; dh < 3; ++dh) {
            int s = srbase + dh; if (s >= ROWS) s -= ROWS;
            rs[dh] = s * HALO_W;
        }

        const char* wls = smem + WOFF;
        #pragma unroll
        for (int dh = 0; dh < 3; ++dh) {
            #pragma unroll
            for (int dw = 0; dw < 3; ++dw) {
                const int tap = dh * 3 + dw;
                bf16x8 b0 = *(const bf16x8*)(wls + (tap * 32 + col16) * 64 + g4 * 16);
                bf16x8 b1 = *(const bf16x8*)(wls + (tap * 32 + 16 + col16) * 64 + g4 * 16);
                #pragma unroll
                for (int m = 0; m < 4; ++m) {
                    int p = rs[dh] + m * 16 + col16 + dw;
                    bf16x8 a = *(const bf16x8*)(smem + xbyte(p, g4));
                    acc[m][0] = __builtin_amdgcn_mfma_f32_16x16x32_bf16(a, b0, acc[m][0], 0, 0, 0);
                    acc[m][1] = __builtin_amdgcn_mfma_f32_16x16x32_bf16(a, b1, acc[m][1], 0, 0, 0);
                }
            }
        }

        // ---- store (nontemporal: output never re-read) ----
        {
            float* orow = ob + (size_t)(hbase + it * 8 + wv) * WWD + w0;
            #pragma unroll
            for (int m = 0; m < 4; ++m) {
                #pragma unroll
                for (int n = 0; n < 2; ++n) {
                    float* pp = orow + (size_t)(n * 16 + col16) * HW + m * 16 + g4 * 4;
                    __builtin_nontemporal_store(acc[m][n], (f32x4*)pp);
                }
            }
        }

        if (it < NITER - 1) {
            __syncthreads();   // all waves done reading LDS tile `it`

            // ---- write rows for iter it+1 (prefetched last tail / prologue) ----
            #pragma unroll
            for (int k = 0; k < 5; ++k) {
                int u = tid + k * 512;
                if (u < NU8) {
                    int g  = u / (8 * HALO_W);
                    int p  = u - g * (8 * HALO_W);
                    int hh = p / HALO_W;
                    int ww = p - hh * HALO_W;
                    int slot = wb + hh; if (slot >= ROWS) slot -= ROWS;
                    int pp = slot * HALO_W + ww;
                    unsigned q0 = (unsigned)f2bf(sv[k][0]) | ((unsigned)f2bf(sv[k][1]) << 16);
                    unsigned q1 = (unsigned)f2bf(sv[k][2]) | ((unsigned)f2bf(sv[k][3]) << 16);
                    unsigned q2 = (unsigned)f2bf(sv[k][4]) | ((unsigned)f2bf(sv[k][5]) << 16);
                    unsigned q3 = (unsigned)f2bf(sv[k][6]) | ((unsigned)f2bf(sv[k][7]) << 16);
                    u32x4 q = { q0, q1, q2, q3 };
                    *(u32x4*)(smem + xbyte(pp, g)) = q;
                }
            }
            wb += 8; if (wb >= ROWS) wb -= ROWS;

            // ---- prefetch rows for iter it+2 (r_rel = 8*it+17+hh) ----
            if (it < NITER - 2) {
                #pragma unroll
                for (int k = 0; k < 5; ++k) {
                    int u = tid + k * 512;
                    if (u < NU8) {
                        int g  = u / (8 * HALO_W);
                        int p  = u - g * (8 * HALO_W);
                        int hh = p / HALO_W;
                        int ww = p - hh * HALO_W;
                        int row = hbase + 8 * it + 17 + hh;
                        int cl  = w0 + ww - 1;
                        bool ok = ((unsigned)row < (unsigned)HH) && ((unsigned)cl < (unsigned)WWD);
                        const float* src = xb + (g * 8) * HW + row * WWD + cl;
                        #pragma unroll
                        for (int j = 0; j < 8; ++j) {
                            float t = 0.f;
                            if (ok) t = src[j * HW];
                            sv[k][j] = t;
                        }
                    }
                }
            }

            __syncthreads();   // tile it+1 ready
        }

        srbase += 8; if (srbase >= ROWS) srbase -= ROWS;
    }
}

extern "C" void kernel_launch(void* const* d_in, const int* in_sizes, int n_in,
                              void* d_out, int out_size, void* d_ws, size_t ws_size,
                              hipStream_t stream) {
    const float* x  = (const float*)d_in[0];
    const float* wk = (const float*)d_in[1];
    float* out = (float*)d_out;
    dim3 grid(WWD / TW, HH / (TH * NITER), 16);  // (8, 4, 16) = 512 blocks
    conv3x3_mfma<<<grid, 512, 0, stream>>>(x, wk, out);
}